// Round 4
// baseline (136.709 us; speedup 1.0000x reference)
//
#include <hip/hip_runtime.h>
#include <hip/hip_bf16.h>

#define NN 50000
#define CC 64
#define KK 20

static __device__ __forceinline__ ushort f2bf(float f) {
    unsigned int u = __float_as_uint(f);
    unsigned int r = (u + 0x7FFFu + ((u >> 16) & 1u)) >> 16;   // RNE
    return (ushort)r;
}
static __device__ __forceinline__ float bfl(unsigned int u) {   // low bf16 -> f32
    return __uint_as_float(u << 16);
}
static __device__ __forceinline__ float bfh(unsigned int u) {   // high bf16 -> f32
    return __uint_as_float(u & 0xffff0000u);
}

// ---------------------------------------------------------------------------
// Kernel 1 (unchanged): yA[n][c] = (W1-W2)@x + b ; yB[n][c] = W2@x,
// node-major bf16 (one node column = 128 B = one cache line).
// ---------------------------------------------------------------------------
__global__ __launch_bounds__(256) void prep_kernel(
    const float* __restrict__ x,   // [64][NN]
    const float* __restrict__ W,   // [64][128]
    const float* __restrict__ b,   // [64]
    ushort* __restrict__ yA,       // [NN][64] bf16
    ushort* __restrict__ yB)       // [NN][64] bf16
{
    __shared__ float At[64][65];
    __shared__ float Bt[64][65];
    __shared__ float xt[64][68];

    const int t = threadIdx.x;
    for (int i = t; i < 64 * 64; i += 256) {
        int c = i >> 6, ci = i & 63;
        float w1 = W[c * 128 + ci];
        float w2 = W[c * 128 + 64 + ci];
        At[ci][c] = w1 - w2;
        Bt[ci][c] = w2;
    }

    const int n0 = blockIdx.x * 64;
    const int g  = t >> 6;
    const int nl = t & 63;
    #pragma unroll
    for (int i = 0; i < 16; i++) {
        int ci = i * 4 + g;
        int nn = n0 + nl;
        xt[ci][nl] = (nn < NN) ? x[ci * NN + nn] : 0.f;
    }
    __syncthreads();

    const int c = t & 63;
    float accA[16], accB[16];
    #pragma unroll
    for (int j = 0; j < 16; j++) { accA[j] = 0.f; accB[j] = 0.f; }

    for (int ci = 0; ci < 64; ci++) {
        float a  = At[ci][c];
        float w2 = Bt[ci][c];
        const float4* xr = reinterpret_cast<const float4*>(&xt[ci][g * 16]);
        #pragma unroll
        for (int q = 0; q < 4; q++) {
            float4 xv = xr[q];
            accA[q * 4 + 0] += a * xv.x;  accB[q * 4 + 0] += w2 * xv.x;
            accA[q * 4 + 1] += a * xv.y;  accB[q * 4 + 1] += w2 * xv.y;
            accA[q * 4 + 2] += a * xv.z;  accB[q * 4 + 2] += w2 * xv.z;
            accA[q * 4 + 3] += a * xv.w;  accB[q * 4 + 3] += w2 * xv.w;
        }
    }

    float bias = b[c];
    #pragma unroll
    for (int j = 0; j < 16; j++) {
        int n = n0 + g * 16 + j;
        if (n < NN) {
            yA[n * 64 + c] = f2bf(accA[j] + bias);
            yB[n * 64 + c] = f2bf(accB[j]);
        }
    }
}

// ---------------------------------------------------------------------------
// Kernel 2: 16 nodes/block, 4 nodes/wave, slot-parallel gather (4 edge slots
// x 16 channel-quads). This version: (a) idx/sup staged in LDS once per node
// (packed i|j<<16; conflict-free broadcast reads) instead of in-loop shfl;
// (b) all 10 gather loads per node issued into register arrays BEFORE any
// unpack -> ~10 outstanding loads/lane for latency hiding.
// ---------------------------------------------------------------------------
__global__ __launch_bounds__(256) void edge_kernel(
    const ushort* __restrict__ yA,   // [NN][64] bf16  (x_i path, edge_index[1])
    const ushort* __restrict__ yB,   // [NN][64] bf16  (x_j path, edge_index[0])
    const int* __restrict__ ej,      // edge_index[0] : [NN][KK]
    const int* __restrict__ ei,      // edge_index[1] : [NN][KK]
    const float* __restrict__ dis,   // [NN][KK]
    const float* __restrict__ att_w, // [KK]
    const float* __restrict__ att_b, // [1]
    float* __restrict__ out)         // [64][NN]
{
    __shared__ float supL[16][KK];       // 2*sigmoid(-d*scaler) per (node,k)
    __shared__ unsigned int ijL[16][KK]; // i | (j<<16)   (both < 50000 < 2^16)
    __shared__ float tile[16][68];

    const int t    = threadIdx.x;
    const int lane = t & 63;
    const int w    = t >> 6;            // wave 0..3
    const int g    = lane >> 4;         // edge slot 0..3
    const int l    = lane & 15;         // channel quad (uint2 within column)
    const int n0   = blockIdx.x * 16;   // grid 3125, no tail

    const float aw = (lane < KK) ? att_w[lane] : 0.f;
    const float ab = att_b[0];

    // ---- Stage phase: each wave stages its own 4 nodes (no barrier needed:
    // producer == consumer wave; compiler orders via lgkmcnt). ----
    #pragma unroll
    for (int s = 0; s < 4; s++) {
        const int nl = w * 4 + s;
        const int n  = n0 + nl;
        float d = 0.f; int ii = 0, jj = 0;
        if (lane < KK) {
            d  = dis[n * KK + lane];
            ii = ei[n * KK + lane];
            jj = ej[n * KK + lane];
        }
        float p = aw * d;
        #pragma unroll
        for (int off = 16; off > 0; off >>= 1) p += __shfl_down(p, off);
        const float scaler = tanhf(__shfl(p, 0) + ab) + 1.0f;
        if (lane < KK) {
            supL[nl][lane] = 2.0f / (1.0f + __expf(d * scaler));
            ijL[nl][lane]  = (unsigned int)ii | ((unsigned int)jj << 16);
        }
    }

    const uint2* A2 = (const uint2*)yA;   // 16 uint2 per node column
    const uint2* B2 = (const uint2*)yB;

    #pragma unroll
    for (int s = 0; s < 4; s++) {
        const int nl = w * 4 + s;

        // broadcast reads: per kb, 4 distinct consecutive dwords, 16-lane
        // broadcast each -> conflict-free
        unsigned int ij[5]; float sp[5];
        #pragma unroll
        for (int kb = 0; kb < 5; kb++) {
            ij[kb] = ijL[nl][kb * 4 + g];
            sp[kb] = supL[nl][kb * 4 + g];
        }

        // issue all 10 gathers before consuming any
        uint2 av[5], bv[5];
        #pragma unroll
        for (int kb = 0; kb < 5; kb++) {
            const unsigned int i_k = ij[kb] & 0xffffu;
            const unsigned int j_k = ij[kb] >> 16;
            av[kb] = A2[(size_t)i_k * 16 + l];
            bv[kb] = B2[(size_t)j_k * 16 + l];
        }

        float4 m = {0.f, 0.f, 0.f, 0.f};
        #pragma unroll
        for (int kb = 0; kb < 5; kb++) {
            const float s_k = sp[kb];
            float v;
            v = fmaxf(bfl(av[kb].x) + bfl(bv[kb].x), 0.f) * s_k;  m.x = fmaxf(m.x, v);
            v = fmaxf(bfh(av[kb].x) + bfh(bv[kb].x), 0.f) * s_k;  m.y = fmaxf(m.y, v);
            v = fmaxf(bfl(av[kb].y) + bfl(bv[kb].y), 0.f) * s_k;  m.z = fmaxf(m.z, v);
            v = fmaxf(bfh(av[kb].y) + bfh(bv[kb].y), 0.f) * s_k;  m.w = fmaxf(m.w, v);
        }

        // max across the 4 slots
        #pragma unroll
        for (int mask = 16; mask <= 32; mask <<= 1) {
            m.x = fmaxf(m.x, __shfl_xor(m.x, mask));
            m.y = fmaxf(m.y, __shfl_xor(m.y, mask));
            m.z = fmaxf(m.z, __shfl_xor(m.z, mask));
            m.w = fmaxf(m.w, __shfl_xor(m.w, mask));
        }
        if (g == 0) *(float4*)&tile[nl][l * 4] = m;
    }
    __syncthreads();

    // out[c][n0..n0+15]; 2-way LDS aliasing only (free).
    #pragma unroll
    for (int it = 0; it < 4; it++) {
        const int c  = it * 16 + (t >> 4);
        const int nl = t & 15;
        out[(size_t)c * NN + n0 + nl] = tile[nl][c];
    }
}

extern "C" void kernel_launch(void* const* d_in, const int* in_sizes, int n_in,
                              void* d_out, int out_size, void* d_ws, size_t ws_size,
                              hipStream_t stream) {
    const float* x     = (const float*)d_in[0];
    const int*   e     = (const int*)d_in[1];    // [2][NN][KK]
    const float* dis   = (const float*)d_in[2];
    const float* W     = (const float*)d_in[3];
    const float* b     = (const float*)d_in[4];
    const float* att_w = (const float*)d_in[5];
    const float* att_b = (const float*)d_in[6];
    float* out = (float*)d_out;

    ushort* yA = (ushort*)d_ws;                  // [NN][64] bf16
    ushort* yB = yA + (size_t)NN * 64;           // [NN][64] bf16 (12.8 MB total)

    prep_kernel<<<(NN + 63) / 64, 256, 0, stream>>>(x, W, b, yA, yB);
    edge_kernel<<<NN / 16, 256, 0, stream>>>(yA, yB, e, e + NN * KK, dis,
                                             att_w, att_b, out);
}